// Round 11
// baseline (359.535 us; speedup 1.0000x reference)
//
#include <hip/hip_runtime.h>
#include <hip/hip_bf16.h>

typedef __attribute__((ext_vector_type(8))) short short8;
typedef __attribute__((ext_vector_type(4))) float f32x4;
typedef __attribute__((ext_vector_type(2))) float f32x2;
typedef unsigned short u16;
typedef unsigned int u32;
typedef unsigned char u8;
typedef unsigned long long u64;
typedef long long i64;

#define NORM_INV (1.0f / 100.0f)

__device__ __forceinline__ float silu(float x) {
    return x * __builtin_amdgcn_rcpf(1.0f + __expf(-x));
}

__device__ __forceinline__ u16 f2bf(float x) {
    union { float f; u32 u; } v; v.f = x;
    u32 r = v.u + 0x7fff + ((v.u >> 16) & 1);   // RNE
    return (u16)(r >> 16);
}

// ---------------- kernel 0: weight transposes (tiny) ----------------
__global__ void prep_weights(const float* __restrict__ W1, const float* __restrict__ W2,
                             u16* __restrict__ W1abT, u8* __restrict__ W2T8) {
    int idx = blockIdx.x * blockDim.x + threadIdx.x;
    if (idx < 256 * 128) {
        int j = idx >> 7, k = idx & 127;
        float v = (j < 128) ? W1[k * 128 + j] : W1[(128 + k) * 128 + (j - 128)];
        W1abT[j * 128 + k] = f2bf(v);
    } else if (idx < 256 * 128 + 128 * 128) {
        int t = idx - 256 * 128;
        int n = t >> 7, k = t & 127;
        float v = W2[k * 128 + n];
        int pk = __builtin_amdgcn_cvt_pk_fp8_f32(v, v, 0, false);
        W2T8[n * 128 + k] = (u8)pk;
    }
}

// ---------------- kernel 1: AB8[node][256] = fp8[h@W1a + b1 | h@W1b] ----------------
__global__ __launch_bounds__(256) void ab_kernel(const float* __restrict__ h,
        const float* __restrict__ b1, const u16* __restrict__ W1abT,
        u8* __restrict__ AB8, int N) {
    __shared__ u16 hs[32 * 128];     // 32 nodes x 128 k, bf16, XOR-swizzled
    int tid = threadIdx.x;
    int n0 = blockIdx.x * 32;
    int lane = tid & 63, wave = tid >> 6;

    #pragma unroll
    for (int it = 0; it < 8; ++it) {
        int item = it * 256 + tid;          // 2048 items, 2 k each
        int m = item >> 6;
        int k = (item & 63) * 2;
        float2 hv = make_float2(0.f, 0.f);
        if (n0 + m < N) hv = *(const float2*)(h + (size_t)(n0 + m) * 128 + k);
        u32 pk = (u32)f2bf(hv.x) | ((u32)f2bf(hv.y) << 16);
        int byteoff = m * 256 + ((k * 2) ^ ((m & 7) << 4));
        *(u32*)((char*)hs + byteoff) = pk;
    }

    short8 bw[4][4];
    #pragma unroll
    for (int nt = 0; nt < 4; ++nt) {
        int j = wave * 64 + nt * 16 + (lane & 15);
        #pragma unroll
        for (int ks = 0; ks < 4; ++ks)
            bw[nt][ks] = *(const short8*)((const char*)W1abT + j * 256 + ks * 64 + (lane >> 4) * 16);
    }
    __syncthreads();

    f32x4 acc[2][4] = {};
    #pragma unroll
    for (int ks = 0; ks < 4; ++ks) {
        short8 a[2];
        #pragma unroll
        for (int mt = 0; mt < 2; ++mt) {
            int row = mt * 16 + (lane & 15);
            int byteoff = row * 256 + (((ks * 64) + ((lane >> 4) * 16)) ^ ((row & 7) << 4));
            a[mt] = *(short8*)((char*)hs + byteoff);
        }
        #pragma unroll
        for (int mt = 0; mt < 2; ++mt)
            #pragma unroll
            for (int nt = 0; nt < 4; ++nt)
                acc[mt][nt] = __builtin_amdgcn_mfma_f32_16x16x32_bf16(a[mt], bw[nt][ks], acc[mt][nt], 0, 0, 0);
    }

    #pragma unroll
    for (int mt = 0; mt < 2; ++mt) {
        #pragma unroll
        for (int nt = 0; nt < 4; ++nt) {
            int j = wave * 64 + nt * 16 + (lane & 15);
            float bias = (j < 128) ? b1[j] : 0.f;
            #pragma unroll
            for (int r = 0; r < 4; ++r) {
                int node = n0 + mt * 16 + (lane >> 4) * 4 + r;
                if (node < N) {
                    float v = acc[mt][nt][r] + bias;
                    int pk = __builtin_amdgcn_cvt_pk_fp8_f32(v, v, 0, false);
                    AB8[(size_t)node * 256 + j] = (u8)pk;
                }
            }
        }
    }
}

// ---------------- CSR build: hist -> hierarchical scan -> scatter ----------------
__global__ void hist_k(const int* __restrict__ eidx, u32* __restrict__ cnt, int E) {
    int e = blockIdx.x * blockDim.x + threadIdx.x;
    if (e < E) atomicAdd(&cnt[eidx[e]], 1u);
}

__global__ void bsum_k(const u32* __restrict__ cnt, u32* __restrict__ bsum, int N) {
    __shared__ u32 red[256];
    int t = threadIdx.x;
    int i = blockIdx.x * 256 + t;
    red[t] = (i < N) ? cnt[i] : 0u;
    __syncthreads();
    for (int off = 128; off > 0; off >>= 1) {
        if (t < off) red[t] += red[t + off];
        __syncthreads();
    }
    if (t == 0) bsum[blockIdx.x] = red[0];
}

__global__ void bscan_k(const u32* __restrict__ bsum, u32* __restrict__ bpref,
                        u32* __restrict__ rowstart, int NB, int N) {
    if (blockIdx.x == 0 && threadIdx.x == 0) {
        u32 r = 0;
        for (int i = 0; i < NB; ++i) { bpref[i] = r; r += bsum[i]; }
        rowstart[N] = r;
    }
}

__global__ void bwrite_k(const u32* __restrict__ cnt, const u32* __restrict__ bpref,
                         u32* __restrict__ rowstart, u32* __restrict__ cur, int N) {
    __shared__ u32 v[256];
    __shared__ u32 p[256];
    int t = threadIdx.x;
    int i = blockIdx.x * 256 + t;
    v[t] = (i < N) ? cnt[i] : 0u;
    __syncthreads();
    if (t == 0) {
        u32 r = bpref[blockIdx.x];
        for (int k = 0; k < 256; ++k) { p[k] = r; r += v[k]; }
    }
    __syncthreads();
    if (i < N) { rowstart[i] = p[t]; cur[i] = p[t]; }
}

__global__ void scatter_k(const int* __restrict__ eidx, const float* __restrict__ edge_attr,
                          const float* __restrict__ edge_mask, const float* __restrict__ coord_diff,
                          u32* __restrict__ cur, int* __restrict__ colS, float* __restrict__ eaS,
                          float* __restrict__ cdxS, float* __restrict__ cdyS, float* __restrict__ cdzS,
                          int E) {
    int e = blockIdx.x * blockDim.x + threadIdx.x;
    if (e < E) {
        int r = eidx[e];
        u32 pos = atomicAdd(&cur[r], 1u);
        colS[pos] = eidx[E + e];
        eaS[pos]  = edge_attr[e];
        float em  = edge_mask[e];
        cdxS[pos] = coord_diff[3 * e]     * em;   // fold mask into cd
        cdyS[pos] = coord_diff[3 * e + 1] * em;
        cdzS[pos] = coord_diff[3 * e + 2] * em;
    }
}

// ---------------- kernel 2: CSR node-centric edge MLP, ZERO float atomics ----------------
// r11: theory = the 2.4M device-scope atomicAdds were the saturated shared
// resource (time invariant across occupancy/bytes/VGPR). One wave per node,
// 16-edge chunks, per-node register accumulation, 3 plain stores per node.
// A-half gather is now wave-uniform (1 row/node, L1-broadcast).
__global__ __launch_bounds__(256) void edge_csr(
        const u8* __restrict__ AB8, const u8* __restrict__ W2T8,
        const u32* __restrict__ rowstart, const int* __restrict__ colS,
        const float* __restrict__ eaS, const float* __restrict__ cdxS,
        const float* __restrict__ cdyS, const float* __restrict__ cdzS,
        const float* __restrict__ W1, const float* __restrict__ b2,
        const float* __restrict__ W3, float* __restrict__ agg, int N) {
    __shared__ u8 w2s8[128 * 128];   // swizzled fp8 W2T copy (16 KB)
    __shared__ float ssc[4][16];     // per-wave scale scratch
    __shared__ float sw1c[128];
    __shared__ float sb2[128];
    __shared__ float sw3[128];

    const int tid = threadIdx.x;
    const int lane = tid & 63;
    const int wv = tid >> 6;
    const int le = lane & 15;        // edge-sub / col-sub
    const int lg = lane >> 4;        // k-chunk group 0..3

    #pragma unroll
    for (int it = 0; it < 8; ++it) {
        int idx = it * 256 + tid;
        int row = idx >> 4, c8 = idx & 15;
        u64 v = *(const u64*)(W2T8 + row * 128 + c8 * 8);
        *(u64*)(w2s8 + row * 128 + ((c8 * 8) ^ ((row & 7) << 4))) = v;
    }
    if (tid < 128) {
        sw1c[tid] = W1[256 * 128 + tid];
        sb2[tid]  = b2[tid];
        sw3[tid]  = W3[tid];
    }
    __syncthreads();                  // only barrier in kernel

    volatile const float* vw1c = sw1c;   // volatile: forbid loop-invariant hoist
    volatile const float* vb2  = sb2;
    volatile const float* vw3  = sw3;

    const int wpb = blockDim.x >> 6;
    const int nwaves = gridDim.x * wpb;

    for (int n = blockIdx.x * wpb + wv; n < N; n += nwaves) {
        u32 p0 = rowstart[n], p1 = rowstart[n + 1];
        float ax = 0.f, ay = 0.f, az = 0.f;

        for (u32 base = p0; base < p1; base += 16) {
            u32 pos = base + le;
            bool valid = pos < p1;
            u32 pc = valid ? pos : (p1 - 1);
            int colv  = colS[pc];
            float eav = valid ? eaS[pc]  : 0.f;
            float cdx = valid ? cdxS[pc] : 0.f;
            float cdy = valid ? cdyS[pc] : 0.f;
            float cdz = valid ? cdzS[pc] : 0.f;

            // gathers: A wave-uniform (L1 broadcast), B random
            uint2 va[4], vb[4];
            {
                const char* rp = (const char*)(AB8 + (size_t)n * 256);
                const char* cp = (const char*)(AB8 + (size_t)colv * 256 + 128);
                #pragma unroll
                for (int ks = 0; ks < 4; ++ks) {
                    va[ks] = *(const uint2*)(rp + ks * 32 + lg * 8);
                    vb[ks] = *(const uint2*)(cp + ks * 32 + lg * 8);
                }
            }

            // convert fp8 -> fp8 A-fragments (layer-1 finish + silu)
            i64 pa[4];
            #pragma unroll
            for (int ks = 0; ks < 4; ++ks) {
                u32 a0 = va[ks].x, a1 = va[ks].y;
                u32 b0 = vb[ks].x, b1_ = vb[ks].y;
                f32x2 fa[4], fb[4];
                fa[0] = __builtin_amdgcn_cvt_pk_f32_fp8(a0, false);
                fa[1] = __builtin_amdgcn_cvt_pk_f32_fp8(a0, true);
                fa[2] = __builtin_amdgcn_cvt_pk_f32_fp8(a1, false);
                fa[3] = __builtin_amdgcn_cvt_pk_f32_fp8(a1, true);
                fb[0] = __builtin_amdgcn_cvt_pk_f32_fp8(b0, false);
                fb[1] = __builtin_amdgcn_cvt_pk_f32_fp8(b0, true);
                fb[2] = __builtin_amdgcn_cvt_pk_f32_fp8(b1_, false);
                fb[3] = __builtin_amdgcn_cvt_pk_f32_fp8(b1_, true);
                float x[8];
                #pragma unroll
                for (int jp = 0; jp < 4; ++jp) {
                    float wcx = vw1c[ks * 32 + lg * 8 + 2 * jp];
                    float wcy = vw1c[ks * 32 + lg * 8 + 2 * jp + 1];
                    x[2 * jp]     = silu(fa[jp].x + fb[jp].x + eav * wcx);
                    x[2 * jp + 1] = silu(fa[jp].y + fb[jp].y + eav * wcy);
                }
                u32 lo = 0, hi = 0;
                lo = __builtin_amdgcn_cvt_pk_fp8_f32(x[0], x[1], lo, false);
                lo = __builtin_amdgcn_cvt_pk_fp8_f32(x[2], x[3], lo, true);
                hi = __builtin_amdgcn_cvt_pk_fp8_f32(x[4], x[5], hi, false);
                hi = __builtin_amdgcn_cvt_pk_fp8_f32(x[6], x[7], hi, true);
                union { uint2 u; i64 l; } c; c.u = make_uint2(lo, hi);
                pa[ks] = c.l;
            }

            // layer 2: fp8 MFMA in two n-halves
            float s[4] = { 0.f, 0.f, 0.f, 0.f };
            #pragma unroll
            for (int hf = 0; hf < 2; ++hf) {
                f32x4 acc[4] = {};
                #pragma unroll
                for (int ks = 0; ks < 4; ++ks) {
                    #pragma unroll
                    for (int nt = 0; nt < 4; ++nt) {
                        int row = (hf * 4 + nt) * 16 + le;
                        u64 b8 = *(const u64*)(w2s8 + row * 128 +
                                 (((ks * 32) + (lg * 8)) ^ ((le & 7) << 4)));
                        acc[nt] = __builtin_amdgcn_mfma_f32_16x16x32_fp8_fp8(pa[ks], (i64)b8, acc[nt], 0, 0, 0);
                    }
                }
                #pragma unroll
                for (int nt = 0; nt < 4; ++nt) {
                    int j = (hf * 4 + nt) * 16 + le;
                    float b2j = vb2[j];
                    float w3j = vw3[j];
                    #pragma unroll
                    for (int r = 0; r < 4; ++r)
                        s[r] += silu(acc[nt][r] + b2j) * w3j;
                }
            }
            #pragma unroll
            for (int r = 0; r < 4; ++r) {
                float t = s[r];
                t += __shfl_xor(t, 1);
                t += __shfl_xor(t, 2);
                t += __shfl_xor(t, 4);
                t += __shfl_xor(t, 8);
                s[r] = t;
            }
            if (le == 0) {
                f32x4 sv = { s[0], s[1], s[2], s[3] };
                *(f32x4*)&ssc[wv][lg * 4] = sv;   // same-wave LDS, lgkmcnt-ordered
            }
            float sc = ssc[wv][le];               // scale for edge le

            // per-node accumulation (all 4 lg groups compute identical sums)
            float px = cdx * sc, py = cdy * sc, pz = cdz * sc;
            px += __shfl_xor(px, 1); px += __shfl_xor(px, 2); px += __shfl_xor(px, 4); px += __shfl_xor(px, 8);
            py += __shfl_xor(py, 1); py += __shfl_xor(py, 2); py += __shfl_xor(py, 4); py += __shfl_xor(py, 8);
            pz += __shfl_xor(pz, 1); pz += __shfl_xor(pz, 2); pz += __shfl_xor(pz, 4); pz += __shfl_xor(pz, 8);
            ax += px; ay += py; az += pz;
        }

        if (lane == 0) {
            agg[3 * n]     = ax;
            agg[3 * n + 1] = ay;
            agg[3 * n + 2] = az;
        }
    }
}

// ---------------- kernel 3: coord update ----------------
__global__ void finalize(const float* __restrict__ coord, const float* __restrict__ agg,
                         const float* __restrict__ node_mask, float* __restrict__ out, int n3) {
    int i = blockIdx.x * blockDim.x + threadIdx.x;
    if (i < n3) {
        int n = i / 3;
        out[i] = (coord[i] + agg[i] * NORM_INV) * node_mask[n];
    }
}

extern "C" void kernel_launch(void* const* d_in, const int* in_sizes, int n_in,
                              void* d_out, int out_size, void* d_ws, size_t ws_size,
                              hipStream_t stream) {
    const float* h          = (const float*)d_in[0];
    const float* coord      = (const float*)d_in[1];
    const int*   eidx       = (const int*)d_in[2];
    const float* coord_diff = (const float*)d_in[3];
    const float* edge_attr  = (const float*)d_in[4];
    const float* node_mask  = (const float*)d_in[5];
    const float* edge_mask  = (const float*)d_in[6];
    const float* W1         = (const float*)d_in[7];
    const float* b1         = (const float*)d_in[8];
    const float* W2         = (const float*)d_in[9];
    const float* b2         = (const float*)d_in[10];
    const float* W3         = (const float*)d_in[11];

    int N = in_sizes[0] / 128;   // 50000
    int E = in_sizes[2] / 2;     // 800000
    int NB = (N + 255) / 256;    // 196

    char* ws = (char*)d_ws;
    size_t off = 0;
    u8*  AB8      = (u8*)(ws + off);  off += (size_t)N * 256;              off = (off + 255) & ~(size_t)255;
    u16* W1abT    = (u16*)(ws + off); off += 256 * 128 * sizeof(u16);
    u8*  W2T8     = (u8*)(ws + off);  off += 128 * 128;                    off = (off + 255) & ~(size_t)255;
    float* agg    = (float*)(ws + off); off += (size_t)N * 3 * sizeof(float); off = (off + 255) & ~(size_t)255;
    u32* cnt      = (u32*)(ws + off); off += (size_t)(N + 256) * 4;
    u32* bsum     = (u32*)(ws + off); off += 256 * 4;
    u32* bpref    = (u32*)(ws + off); off += 260 * 4;
    u32* rowstart = (u32*)(ws + off); off += (size_t)(N + 4) * 4;
    u32* cur      = (u32*)(ws + off); off += (size_t)(N + 4) * 4;          off = (off + 255) & ~(size_t)255;
    int* colS     = (int*)(ws + off); off += (size_t)E * 4;
    float* eaS    = (float*)(ws + off); off += (size_t)E * 4;
    float* cdxS   = (float*)(ws + off); off += (size_t)E * 4;
    float* cdyS   = (float*)(ws + off); off += (size_t)E * 4;
    float* cdzS   = (float*)(ws + off); off += (size_t)E * 4;

    hipMemsetAsync(cnt, 0, (size_t)(N + 256) * 4, stream);
    hipLaunchKernelGGL(prep_weights, dim3(192), dim3(256), 0, stream, W1, W2, W1abT, W2T8);
    hipLaunchKernelGGL(ab_kernel, dim3((N + 31) / 32), dim3(256), 0, stream, h, b1, W1abT, AB8, N);
    hipLaunchKernelGGL(hist_k, dim3((E + 255) / 256), dim3(256), 0, stream, eidx, cnt, E);
    hipLaunchKernelGGL(bsum_k, dim3(NB), dim3(256), 0, stream, cnt, bsum, N);
    hipLaunchKernelGGL(bscan_k, dim3(1), dim3(64), 0, stream, bsum, bpref, rowstart, NB, N);
    hipLaunchKernelGGL(bwrite_k, dim3(NB), dim3(256), 0, stream, cnt, bpref, rowstart, cur, N);
    hipLaunchKernelGGL(scatter_k, dim3((E + 255) / 256), dim3(256), 0, stream,
                       eidx, edge_attr, edge_mask, coord_diff, cur, colS, eaS, cdxS, cdyS, cdzS, E);
    hipLaunchKernelGGL(edge_csr, dim3(2048), dim3(256), 0, stream,
                       AB8, W2T8, rowstart, colS, eaS, cdxS, cdyS, cdzS, W1, b2, W3, agg, N);
    int n3 = N * 3;
    hipLaunchKernelGGL(finalize, dim3((n3 + 255) / 256), dim3(256), 0, stream,
                       coord, agg, node_mask, (float*)d_out, n3);
}

// Round 12
// 184.361 us; speedup vs baseline: 1.9502x; 1.9502x over previous
//
#include <hip/hip_runtime.h>
#include <hip/hip_bf16.h>

typedef __attribute__((ext_vector_type(8))) short short8;
typedef __attribute__((ext_vector_type(4))) float f32x4;
typedef __attribute__((ext_vector_type(2))) float f32x2;
typedef unsigned short u16;
typedef unsigned int u32;
typedef unsigned char u8;
typedef unsigned long long u64;
typedef long long i64;

#define NORM_INV (1.0f / 100.0f)

__device__ __forceinline__ float silu(float x) {
    return x * __builtin_amdgcn_rcpf(1.0f + __expf(-x));
}

__device__ __forceinline__ u16 f2bf(float x) {
    union { float f; u32 u; } v; v.f = x;
    u32 r = v.u + 0x7fff + ((v.u >> 16) & 1);   // RNE
    return (u16)(r >> 16);
}

// ---------------- kernel 0: weight transposes (tiny) ----------------
__global__ void prep_weights(const float* __restrict__ W1, const float* __restrict__ W2,
                             u16* __restrict__ W1abT, u8* __restrict__ W2T8) {
    int idx = blockIdx.x * blockDim.x + threadIdx.x;
    if (idx < 256 * 128) {
        int j = idx >> 7, k = idx & 127;
        float v = (j < 128) ? W1[k * 128 + j] : W1[(128 + k) * 128 + (j - 128)];
        W1abT[j * 128 + k] = f2bf(v);
    } else if (idx < 256 * 128 + 128 * 128) {
        int t = idx - 256 * 128;
        int n = t >> 7, k = t & 127;
        float v = W2[k * 128 + n];
        int pk = __builtin_amdgcn_cvt_pk_fp8_f32(v, v, 0, false);
        W2T8[n * 128 + k] = (u8)pk;
    }
}

// ---------------- kernel 1: AB8[node][256] = fp8[h@W1a + b1 | h@W1b] ----------------
__global__ __launch_bounds__(256) void ab_kernel(const float* __restrict__ h,
        const float* __restrict__ b1, const u16* __restrict__ W1abT,
        u8* __restrict__ AB8, int N) {
    __shared__ u16 hs[32 * 128];     // 32 nodes x 128 k, bf16, XOR-swizzled
    int tid = threadIdx.x;
    int n0 = blockIdx.x * 32;
    int lane = tid & 63, wave = tid >> 6;

    #pragma unroll
    for (int it = 0; it < 8; ++it) {
        int item = it * 256 + tid;          // 2048 items, 2 k each
        int m = item >> 6;
        int k = (item & 63) * 2;
        float2 hv = make_float2(0.f, 0.f);
        if (n0 + m < N) hv = *(const float2*)(h + (size_t)(n0 + m) * 128 + k);
        u32 pk = (u32)f2bf(hv.x) | ((u32)f2bf(hv.y) << 16);
        int byteoff = m * 256 + ((k * 2) ^ ((m & 7) << 4));
        *(u32*)((char*)hs + byteoff) = pk;
    }

    short8 bw[4][4];
    #pragma unroll
    for (int nt = 0; nt < 4; ++nt) {
        int j = wave * 64 + nt * 16 + (lane & 15);
        #pragma unroll
        for (int ks = 0; ks < 4; ++ks)
            bw[nt][ks] = *(const short8*)((const char*)W1abT + j * 256 + ks * 64 + (lane >> 4) * 16);
    }
    __syncthreads();

    f32x4 acc[2][4] = {};
    #pragma unroll
    for (int ks = 0; ks < 4; ++ks) {
        short8 a[2];
        #pragma unroll
        for (int mt = 0; mt < 2; ++mt) {
            int row = mt * 16 + (lane & 15);
            int byteoff = row * 256 + (((ks * 64) + ((lane >> 4) * 16)) ^ ((row & 7) << 4));
            a[mt] = *(short8*)((char*)hs + byteoff);
        }
        #pragma unroll
        for (int mt = 0; mt < 2; ++mt)
            #pragma unroll
            for (int nt = 0; nt < 4; ++nt)
                acc[mt][nt] = __builtin_amdgcn_mfma_f32_16x16x32_bf16(a[mt], bw[nt][ks], acc[mt][nt], 0, 0, 0);
    }

    #pragma unroll
    for (int mt = 0; mt < 2; ++mt) {
        #pragma unroll
        for (int nt = 0; nt < 4; ++nt) {
            int j = wave * 64 + nt * 16 + (lane & 15);
            float bias = (j < 128) ? b1[j] : 0.f;
            #pragma unroll
            for (int r = 0; r < 4; ++r) {
                int node = n0 + mt * 16 + (lane >> 4) * 4 + r;
                if (node < N) {
                    float v = acc[mt][nt][r] + bias;
                    int pk = __builtin_amdgcn_cvt_pk_fp8_f32(v, v, 0, false);
                    AB8[(size_t)node * 256 + j] = (u8)pk;
                }
            }
        }
    }
}

// fp8 gather pair + layer-1 finish + silu -> fp8 A-fragment
__device__ __forceinline__ i64 conv_frag(uint2 va, uint2 vb, float eac, int ks, int lg,
                                         volatile const float* vw1c) {
    f32x2 fa[4], fb[4];
    fa[0] = __builtin_amdgcn_cvt_pk_f32_fp8(va.x, false);
    fa[1] = __builtin_amdgcn_cvt_pk_f32_fp8(va.x, true);
    fa[2] = __builtin_amdgcn_cvt_pk_f32_fp8(va.y, false);
    fa[3] = __builtin_amdgcn_cvt_pk_f32_fp8(va.y, true);
    fb[0] = __builtin_amdgcn_cvt_pk_f32_fp8(vb.x, false);
    fb[1] = __builtin_amdgcn_cvt_pk_f32_fp8(vb.x, true);
    fb[2] = __builtin_amdgcn_cvt_pk_f32_fp8(vb.y, false);
    fb[3] = __builtin_amdgcn_cvt_pk_f32_fp8(vb.y, true);
    float x[8];
    #pragma unroll
    for (int jp = 0; jp < 4; ++jp) {
        float wcx = vw1c[ks * 32 + lg * 8 + 2 * jp];
        float wcy = vw1c[ks * 32 + lg * 8 + 2 * jp + 1];
        x[2 * jp]     = silu(fa[jp].x + fb[jp].x + eac * wcx);
        x[2 * jp + 1] = silu(fa[jp].y + fb[jp].y + eac * wcy);
    }
    u32 lo = 0, hi = 0;
    lo = __builtin_amdgcn_cvt_pk_fp8_f32(x[0], x[1], lo, false);
    lo = __builtin_amdgcn_cvt_pk_fp8_f32(x[2], x[3], lo, true);
    hi = __builtin_amdgcn_cvt_pk_fp8_f32(x[4], x[5], hi, false);
    hi = __builtin_amdgcn_cvt_pk_fp8_f32(x[6], x[7], hi, true);
    union { uint2 u; i64 l; } c; c.u = make_uint2(lo, hi);
    return c.l;
}

// ---------------- kernel 2: dual-subtile (32-edge) wave-autonomous edge MLP ----------------
// r12: per-wave ILP — two independent 16-edge pipelines per iteration. Both
// subtiles' gathers issue up front; convert-A covers gather-B's latency,
// MFMA/epilogue-A covers the rest. fp8 state keeps peak live <=~110 VGPR.
__global__ __launch_bounds__(256) void edge_kernel(
        const u8* __restrict__ AB8, const u8* __restrict__ W2T8,
        const int* __restrict__ eidx, const float* __restrict__ coord_diff,
        const float* __restrict__ edge_attr, const float* __restrict__ edge_mask,
        const float* __restrict__ W1, const float* __restrict__ b2,
        const float* __restrict__ W3, float* __restrict__ agg, int E) {
    __shared__ u8 w2s8[128 * 128];   // swizzled fp8 W2T copy (16 KB)
    __shared__ float ssc[4][2][16];  // per-wave, per-subtile scale scratch
    __shared__ float sw1c[128];
    __shared__ float sb2[128];
    __shared__ float sw3[128];

    const int tid = threadIdx.x;
    const int lane = tid & 63;
    const int wv = tid >> 6;
    const int le = lane & 15;        // edge-sub / col-sub
    const int lg = lane >> 4;        // k-chunk group 0..3

    #pragma unroll
    for (int it = 0; it < 8; ++it) {
        int idx = it * 256 + tid;
        int row = idx >> 4, c8 = idx & 15;
        u64 v = *(const u64*)(W2T8 + row * 128 + c8 * 8);
        *(u64*)(w2s8 + row * 128 + ((c8 * 8) ^ ((row & 7) << 4))) = v;
    }
    if (tid < 128) {
        sw1c[tid] = W1[256 * 128 + tid];
        sb2[tid]  = b2[tid];
        sw3[tid]  = W3[tid];
    }
    __syncthreads();                  // only barrier in kernel

    volatile const float* vw1c = sw1c;   // volatile: forbid loop-invariant hoist
    volatile const float* vb2  = sb2;
    volatile const float* vw3  = sw3;

    const int ntiles = (E + 31) >> 5;
    const int wpb = blockDim.x >> 6;
    const int nwaves = gridDim.x * wpb;
    int tile = blockIdx.x * wpb + wv;
    if (tile >= ntiles) return;

    // ---- prologue: meta(t0) for both subtiles
    int e0 = tile << 5;
    int rowc[2], colc[2];
    float eac[2];
    #pragma unroll
    for (int st = 0; st < 2; ++st) {
        int ep = min(e0 + st * 16 + le, E - 1);
        rowc[st] = eidx[ep]; colc[st] = eidx[E + ep]; eac[st] = edge_attr[ep];
    }

    while (true) {
        // issue gathers for BOTH subtiles (independent chains)
        uint2 va[2][4], vb[2][4];
        #pragma unroll
        for (int st = 0; st < 2; ++st) {
            const char* rp = (const char*)(AB8 + (size_t)rowc[st] * 256);
            const char* cp = (const char*)(AB8 + (size_t)colc[st] * 256 + 128);
            #pragma unroll
            for (int ks = 0; ks < 4; ++ks) {
                va[st][ks] = *(const uint2*)(rp + ks * 32 + lg * 8);
                vb[st][ks] = *(const uint2*)(cp + ks * 32 + lg * 8);
            }
        }
        // mask/coord_diff (used only at scatter; latency hides under converts)
        float emc[2], cdc[2];
        #pragma unroll
        for (int st = 0; st < 2; ++st) {
            emc[st] = edge_mask[min(e0 + st * 16 + le, E - 1)];
            cdc[st] = coord_diff[min(e0 * 3 + st * 48 + lane, E * 3 - 1)];
        }

        // issue meta(next)
        int next = tile + nwaves;
        bool hn = next < ntiles;
        int ne0 = (hn ? next : tile) << 5;
        int rown[2], coln[2];
        float ean[2];
        #pragma unroll
        for (int st = 0; st < 2; ++st) {
            int ep = min(ne0 + st * 16 + le, E - 1);
            rown[st] = eidx[ep]; coln[st] = eidx[E + ep]; ean[st] = edge_attr[ep];
        }

        // convert A then B (convert-A covers gather-B latency)
        i64 pa[2][4];
        #pragma unroll
        for (int st = 0; st < 2; ++st)
            #pragma unroll
            for (int ks = 0; ks < 4; ++ks)
                pa[st][ks] = conv_frag(va[st][ks], vb[st][ks], eac[st], ks, lg, vw1c);

        // per-subtile: layer-2 fp8 MFMA + epilogue + scatter
        #pragma unroll
        for (int st = 0; st < 2; ++st) {
            float s[4] = { 0.f, 0.f, 0.f, 0.f };
            #pragma unroll
            for (int hf = 0; hf < 2; ++hf) {
                f32x4 acc[4] = {};
                #pragma unroll
                for (int ks = 0; ks < 4; ++ks) {
                    #pragma unroll
                    for (int nt = 0; nt < 4; ++nt) {
                        int row = (hf * 4 + nt) * 16 + le;
                        u64 b8 = *(const u64*)(w2s8 + row * 128 +
                                 (((ks * 32) + (lg * 8)) ^ ((le & 7) << 4)));
                        acc[nt] = __builtin_amdgcn_mfma_f32_16x16x32_fp8_fp8(pa[st][ks], (i64)b8, acc[nt], 0, 0, 0);
                    }
                }
                #pragma unroll
                for (int nt = 0; nt < 4; ++nt) {
                    int j = (hf * 4 + nt) * 16 + le;
                    float b2j = vb2[j];
                    float w3j = vw3[j];
                    #pragma unroll
                    for (int r = 0; r < 4; ++r)
                        s[r] += silu(acc[nt][r] + b2j) * w3j;
                }
            }
            #pragma unroll
            for (int r = 0; r < 4; ++r) {
                float t = s[r];
                t += __shfl_xor(t, 1);
                t += __shfl_xor(t, 2);
                t += __shfl_xor(t, 4);
                t += __shfl_xor(t, 8);
                s[r] = t;                 // edge lg*4+r of this subtile
            }
            if (le == 0) {
                f32x4 sv = { s[0], s[1], s[2], s[3] };
                *(f32x4*)&ssc[wv][st][lg * 4] = sv;   // same-wave LDS ordering
            }

            // scatter: 3 atomics per edge (lanes 0..47)
            int els = (lane < 48) ? (lane / 3) : 0;
            int rA = __shfl(rowc[st], els);
            float emA = __shfl(emc[st], els);
            float sc = ssc[wv][st][els];
            int esub = e0 + st * 16 + els;
            if (lane < 48 && esub < E)
                atomicAdd(&agg[rA * 3 + (lane - els * 3)], cdc[st] * emA * sc);
        }

        if (!hn) break;
        tile = next; e0 = ne0;
        #pragma unroll
        for (int st = 0; st < 2; ++st) {
            rowc[st] = rown[st]; colc[st] = coln[st]; eac[st] = ean[st];
        }
    }
}

// ---------------- kernel 3: coord update ----------------
__global__ void finalize(const float* __restrict__ coord, const float* __restrict__ agg,
                         const float* __restrict__ node_mask, float* __restrict__ out, int n3) {
    int i = blockIdx.x * blockDim.x + threadIdx.x;
    if (i < n3) {
        int n = i / 3;
        out[i] = (coord[i] + agg[i] * NORM_INV) * node_mask[n];
    }
}

extern "C" void kernel_launch(void* const* d_in, const int* in_sizes, int n_in,
                              void* d_out, int out_size, void* d_ws, size_t ws_size,
                              hipStream_t stream) {
    const float* h          = (const float*)d_in[0];
    const float* coord      = (const float*)d_in[1];
    const int*   eidx       = (const int*)d_in[2];
    const float* coord_diff = (const float*)d_in[3];
    const float* edge_attr  = (const float*)d_in[4];
    const float* node_mask  = (const float*)d_in[5];
    const float* edge_mask  = (const float*)d_in[6];
    const float* W1         = (const float*)d_in[7];
    const float* b1         = (const float*)d_in[8];
    const float* W2         = (const float*)d_in[9];
    const float* b2         = (const float*)d_in[10];
    const float* W3         = (const float*)d_in[11];

    int N = in_sizes[0] / 128;   // 50000
    int E = in_sizes[2] / 2;     // 800000

    char* ws = (char*)d_ws;
    size_t off = 0;
    u8*  AB8   = (u8*)(ws + off);  off += (size_t)N * 256; off = (off + 255) & ~(size_t)255;
    u16* W1abT = (u16*)(ws + off); off += 256 * 128 * sizeof(u16);
    u8*  W2T8  = (u8*)(ws + off);  off += 128 * 128; off = (off + 255) & ~(size_t)255;
    float* agg = (float*)(ws + off); off += (size_t)N * 3 * sizeof(float);

    hipMemsetAsync(agg, 0, (size_t)N * 3 * sizeof(float), stream);
    hipLaunchKernelGGL(prep_weights, dim3(192), dim3(256), 0, stream, W1, W2, W1abT, W2T8);
    hipLaunchKernelGGL(ab_kernel, dim3((N + 31) / 32), dim3(256), 0, stream, h, b1, W1abT, AB8, N);
    hipLaunchKernelGGL(edge_kernel, dim3(2048), dim3(256), 0, stream,
                       AB8, W2T8, eidx, coord_diff, edge_attr, edge_mask, W1, b2, W3, agg, E);
    int n3 = N * 3;
    hipLaunchKernelGGL(finalize, dim3((n3 + 255) / 256), dim3(256), 0, stream,
                       coord, agg, node_mask, (float*)d_out, n3);
}